// Round 10
// baseline (150.635 us; speedup 1.0000x reference)
//
#include <hip/hip_runtime.h>
#include <stdint.h>

#define HEADS 4
#define DHEAD 32
#define NTOK  4096
#define CDIM  256
#define HID   128
#define NBATCH 4

typedef __bf16 bf16x8 __attribute__((ext_vector_type(8)));
typedef __bf16 bf16x4 __attribute__((ext_vector_type(4)));
typedef float  f32x4  __attribute__((ext_vector_type(4)));

// softmax scale folded with log2(e) into Q so scores are in base-2 domain
#define QSCALE (0.17677669529663689f * 1.4426950408889634f)

#define MFMA __builtin_amdgcn_mfma_f32_16x16x32_bf16

// async global->LDS DMA, 16B per lane; LDS dest = uniform base + lane*16
#define ASYNC16(gp, lp)                                                        \
    __builtin_amdgcn_global_load_lds(                                          \
        (const __attribute__((address_space(1))) unsigned int*)(gp),           \
        (__attribute__((address_space(3))) unsigned int*)(lp), 16, 0, 0)

// ---------------------------------------------------------------------------
// qkv_fused: cast_x + qkv_gemm in one kernel.  Grid 64 p-tiles x 4 b.
// Phase A: DMA x[b][c][p0..p0+64) fp32 tile -> LDS Xf[c][p] (64 KB).
// Phase B: in-LDS transpose-cast -> Xs[p][c] bf16, 16B-chunk XOR swizzle.
// Phase C: 6 o-tiles of 64: af from fp32 weights (in-reg cvt), 32 MFMAs each.
// x read once; Xt intermediate eliminated.
// ---------------------------------------------------------------------------
__global__ __launch_bounds__(256) void qkv_fused(
    const float* __restrict__ x, const float* __restrict__ wq,
    __bf16* __restrict__ Q, __bf16* __restrict__ K, __bf16* __restrict__ Vt)
{
    __shared__ float  Xf[256 * 64];      // [c][p] fp32, 64 KB
    __shared__ __bf16 Xs[64 * 256];      // [p][c] bf16 swizzled, 32 KB

    const int t  = threadIdx.x;
    const int p0 = blockIdx.x * 64;      // 64 tiles
    const int b  = blockIdx.y;           // 4
    const int l = t & 63, lm = l & 15, q4 = l >> 4;
    const int w = __builtin_amdgcn_readfirstlane(t >> 6);

    // Phase A: 16 rounds x (4 waves x 1 KB).  Row c = 256 B = 16 lanes.
#pragma unroll
    for (int i = 0; i < 16; ++i) {
        const int c = (i * 4 + w) * 4 + (l >> 4);
        const float* gp = x + ((size_t)(b * CDIM + c)) * NTOK + p0 + (l & 15) * 4;
        ASYNC16(gp, (char*)Xf + (i * 4 + w) * 1024);
    }
    __syncthreads();

    // Phase B: transpose-cast.  Lanes span p (2-way banks, free).
#pragma unroll
    for (int m = 0; m < 8; ++m) {
        const int p  = t & 63;
        const int c8 = (t >> 6) + 4 * m;             // 0..31
        bf16x8 o;
#pragma unroll
        for (int u = 0; u < 8; ++u) o[u] = (__bf16)Xf[(c8 * 8 + u) * 64 + p];
        const int cc = c8 ^ (p & 7);
        *(bf16x8*)((char*)Xs + p * 512 + cc * 16) = o;
    }
    __syncthreads();

    // Phase C: all 384 outputs.  Per wave: 6 x (16 o x 64 p), K=256.
#pragma unroll 1
    for (int ot = 0; ot < 6; ++ot) {
        const int o0w = ot * 64 + w * 16;
        bf16x8 af[8];
#pragma unroll
        for (int kt = 0; kt < 8; ++kt) {
            const float* wr = wq + (size_t)(o0w + lm) * CDIM + kt * 32 + q4 * 8;
            f32x4 w0 = *(const f32x4*)wr;
            f32x4 w1 = *(const f32x4*)(wr + 4);
#pragma unroll
            for (int u = 0; u < 4; ++u) {
                af[kt][u]     = (__bf16)w0[u];
                af[kt][u + 4] = (__bf16)w1[u];
            }
        }
        f32x4 acc[4] = {};
#pragma unroll
        for (int kt = 0; kt < 8; ++kt) {
#pragma unroll
            for (int nf = 0; nf < 4; ++nf) {
                const int p = nf * 16 + lm;
                bf16x8 bf = *(const bf16x8*)(
                    (const char*)Xs + p * 512 + (((kt * 4 + q4) ^ (lm & 7)) * 16));
                acc[nf] = MFMA(af[kt], bf, acc[nf], 0, 0, 0);
            }
        }

        const int og0  = o0w + q4 * 4;   // r=0..3 stay in one head
        const int which = og0 >> 7;
        const int head  = (og0 >> 5) & 3;
        const int d0    = og0 & 31;
        const int bh    = b * HEADS + head;
#pragma unroll
        for (int nf = 0; nf < 4; ++nf) {
            const int p_g = p0 + nf * 16 + lm;
            f32x4 a = acc[nf];
            if (which == 0) {
                bf16x4 pk = { (__bf16)(a[0] * QSCALE), (__bf16)(a[1] * QSCALE),
                              (__bf16)(a[2] * QSCALE), (__bf16)(a[3] * QSCALE) };
                *(bf16x4*)(Q + ((size_t)bh * NTOK + p_g) * DHEAD + d0) = pk;
            } else if (which == 1) {
                bf16x4 pk = { (__bf16)a[0], (__bf16)a[1], (__bf16)a[2], (__bf16)a[3] };
                *(bf16x4*)(K + ((size_t)bh * NTOK + p_g) * DHEAD + d0) = pk;
            } else {
#pragma unroll
                for (int r = 0; r < 4; ++r)
                    Vt[((size_t)(bh * DHEAD + d0 + r)) * NTOK + p_g] = (__bf16)a[r];
            }
        }
    }
}

// ---------------------------------------------------------------------------
// attn (unchanged R9): LDS-staged, double-buffered, split-j x4, g=4 row
// groups per wave (256 Q rows/block); bf16 partials; ones-MFMA row sums.
// ---------------------------------------------------------------------------
__global__ __launch_bounds__(256, 4) void attn(
    const __bf16* __restrict__ Q, const __bf16* __restrict__ K,
    const __bf16* __restrict__ Vt, __bf16* __restrict__ Opart,
    float* __restrict__ Lsum)
{
    __shared__ uint4  KbufU[2][256];               // [buf][64 rows x 64 B]
    __shared__ uint4  VbufU[2][256];               // [buf][32 rows x 128 B]
    __shared__ __bf16 Ps[4][16][72];               // per-wave P rows (i=lm)

    const int t   = threadIdx.x;
    const int blk = blockIdx.x;                    // 1024
    const int bh  = blk & 15;
    const int rest = blk >> 4;                     // 0..63
    const int qt   = rest & 15;                    // 16 tiles of 256 rows
    const int sp   = rest >> 4;                    // j-split 0..3
    const int l = t & 63, lm = l & 15, q4 = l >> 4;
    const int wu = __builtin_amdgcn_readfirstlane(t >> 6);
    const int row0 = qt * 256 + wu * 64;

    const int jt0 = sp * 16, jt1 = jt0 + 16;

    bf16x8 qf[4];
#pragma unroll
    for (int g = 0; g < 4; ++g)
        qf[g] = *(const bf16x8*)(Q + ((size_t)bh * NTOK + row0 + g * 16 + lm) * DHEAD + q4 * 8);

    const char* KbT = (const char*)(K  + (size_t)bh * NTOK * DHEAD);
    const char* VbT = (const char*)(Vt + (size_t)bh * DHEAD * NTOK);

    const int sK_r  = wu * 16 + (l >> 2);
    const int sK_gc = (l & 3) ^ ((sK_r >> 1) & 3);
    const int sV_r  = wu * 8 + (l >> 3);
    const int sV_gc = (l & 7) ^ (sV_r & 7);

    bf16x8 ones;
#pragma unroll
    for (int u = 0; u < 8; ++u) ones[u] = (__bf16)1.0f;

    f32x4 o[4][3] = {};

    {
        const int j00 = jt0 * 64;
        const char* gk = KbT + (size_t)(j00 + sK_r) * 64 + sK_gc * 16;
        ASYNC16(gk, (char*)&KbufU[0][0] + wu * 1024);
        const char* gv = VbT + (size_t)sV_r * (NTOK * 2) + (size_t)j00 * 2 + sV_gc * 16;
        ASYNC16(gv, (char*)&VbufU[0][0] + wu * 1024);
    }
    __syncthreads();

    for (int jt = jt0; jt < jt1; ++jt) {
        const int buf = (jt - jt0) & 1;
        if (jt + 1 < jt1) {
            const int j0n = (jt + 1) * 64;
            const char* gk = KbT + (size_t)(j0n + sK_r) * 64 + sK_gc * 16;
            ASYNC16(gk, (char*)&KbufU[buf ^ 1][0] + wu * 1024);
            const char* gv = VbT + (size_t)sV_r * (NTOK * 2) + (size_t)j0n * 2 + sV_gc * 16;
            ASYNC16(gv, (char*)&VbufU[buf ^ 1][0] + wu * 1024);
        }

        const __bf16* Kl = (const __bf16*)&KbufU[buf][0];
        const __bf16* Vl = (const __bf16*)&VbufU[buf][0];

        bf16x8 kf[4];
#pragma unroll
        for (int j4 = 0; j4 < 4; ++j4) {
            int jl = j4 * 16 + lm;
            int cs = q4 ^ ((jl >> 1) & 3);
            kf[j4] = *(const bf16x8*)(Kl + jl * 32 + cs * 8);
        }
        const int swv = lm & 7;
        bf16x8 vf[4];
        vf[0] = *(const bf16x8*)(Vl + lm * 64        + ((q4    ) ^ swv) * 8);
        vf[1] = *(const bf16x8*)(Vl + (16 + lm) * 64 + ((q4    ) ^ swv) * 8);
        vf[2] = *(const bf16x8*)(Vl + lm * 64        + ((4 + q4) ^ swv) * 8);
        vf[3] = *(const bf16x8*)(Vl + (16 + lm) * 64 + ((4 + q4) ^ swv) * 8);

#pragma unroll
        for (int g = 0; g < 4; ++g) {
            f32x4 st[4];
#pragma unroll
            for (int j4 = 0; j4 < 4; ++j4) {
                f32x4 z = {};
                st[j4] = MFMA(kf[j4], qf[g], z, 0, 0, 0);
            }
#pragma unroll
            for (int j4 = 0; j4 < 4; ++j4) {
                bf16x4 pk;
                pk[0] = (__bf16)__builtin_amdgcn_exp2f(st[j4][0]);
                pk[1] = (__bf16)__builtin_amdgcn_exp2f(st[j4][1]);
                pk[2] = (__bf16)__builtin_amdgcn_exp2f(st[j4][2]);
                pk[3] = (__bf16)__builtin_amdgcn_exp2f(st[j4][3]);
                *(bf16x4*)&Ps[wu][lm][j4 * 16 + q4 * 4] = pk;
            }
#pragma unroll
            for (int jc = 0; jc < 2; ++jc) {
                bf16x8 pf = *(const bf16x8*)&Ps[wu][lm][jc * 32 + q4 * 8];
                o[g][0] = MFMA(pf, vf[jc * 2 + 0], o[g][0], 0, 0, 0);
                o[g][1] = MFMA(pf, vf[jc * 2 + 1], o[g][1], 0, 0, 0);
                o[g][2] = MFMA(pf, ones,           o[g][2], 0, 0, 0);
            }
        }
        __syncthreads();
    }

    const int b = bh >> 2, h = bh & 3;
    __bf16* Op = Opart + (size_t)sp * NBATCH * NTOK * HID;
#pragma unroll
    for (int g = 0; g < 4; ++g) {
        const int rowg0 = row0 + g * 16;
        if (lm == 0)
            *(f32x4*)(Lsum + ((size_t)sp * 16 + bh) * NTOK + rowg0 + q4 * 4) = o[g][2];
#pragma unroll
        for (int r = 0; r < 4; ++r) {
            size_t rowg = (size_t)b * NTOK + rowg0 + q4 * 4 + r;
            Op[rowg * HID + h * DHEAD + lm]      = (__bf16)o[g][0][r];
            Op[rowg * HID + h * DHEAD + 16 + lm] = (__bf16)o[g][1][r];
        }
    }
}

// ---------------------------------------------------------------------------
// out_fused: combine + out_gemm.  Grid 64 p-tiles x 4 b, block 256.
// Staging: sum 4 bf16 partials (fp32), normalize by sum of 4 Lsums, cast to
// bf16 into swizzled LDS tile (64p x 128c = 16 KB).  GEMM: all 256 o.
// ---------------------------------------------------------------------------
__global__ __launch_bounds__(256) void out_fused(
    const float* __restrict__ wo, const __bf16* __restrict__ Opart,
    const float* __restrict__ Lsum, const float* __restrict__ bias,
    float* __restrict__ out)
{
    __shared__ __bf16 Bs[64 * 128];      // 16 KB, swizzled

    const int t  = threadIdx.x;
    const int p0 = blockIdx.x * 64;      // 64 tiles
    const int b  = blockIdx.y;           // 4
    const int l = t & 63, lm = l & 15, q4 = l >> 4;
    const int w = __builtin_amdgcn_readfirstlane(t >> 6);

    const size_t per = (size_t)NBATCH * NTOK * HID;

    // staging + fused combine: tasks p(64) x c8(16), 4 per thread
#pragma unroll
    for (int m = 0; m < 4; ++m) {
        const int c8 = t & 15;
        const int p  = (t >> 4) + 16 * m;
        const int head = c8 >> 2;
        const size_t li = ((size_t)(b * HEADS + head)) * NTOK + p0 + p;
        const float inv = 1.f / (Lsum[li] + Lsum[li + 16 * NTOK] +
                                 Lsum[li + 32 * NTOK] + Lsum[li + 48 * NTOK]);
        const size_t base = ((size_t)(b * NTOK + p0 + p)) * HID + c8 * 8;
        bf16x8 x0 = *(const bf16x8*)(Opart + base);
        bf16x8 x1 = *(const bf16x8*)(Opart + per + base);
        bf16x8 x2 = *(const bf16x8*)(Opart + 2 * per + base);
        bf16x8 x3 = *(const bf16x8*)(Opart + 3 * per + base);
        bf16x8 o;
#pragma unroll
        for (int u = 0; u < 8; ++u)
            o[u] = (__bf16)((((float)x0[u] + (float)x1[u]) +
                             ((float)x2[u] + (float)x3[u])) * inv);
        const int cc = c8 ^ (p & 7);
        *(bf16x8*)((char*)Bs + p * 256 + cc * 16) = o;
    }
    __syncthreads();

    // GEMM: wave w owns o = w*64 .. +63 (4 groups of 16), K=128
#pragma unroll
    for (int mt = 0; mt < 4; ++mt) {
        const int o0 = w * 64 + mt * 16;
        bf16x8 af[4];
#pragma unroll
        for (int kt = 0; kt < 4; ++kt) {
            const float* wr = wo + (size_t)(o0 + lm) * HID + kt * 32 + q4 * 8;
            f32x4 w0 = *(const f32x4*)wr;
            f32x4 w1 = *(const f32x4*)(wr + 4);
#pragma unroll
            for (int u = 0; u < 4; ++u) {
                af[kt][u]     = (__bf16)w0[u];
                af[kt][u + 4] = (__bf16)w1[u];
            }
        }
        f32x4 acc[4] = {};
#pragma unroll
        for (int kt = 0; kt < 4; ++kt) {
#pragma unroll
            for (int nf = 0; nf < 4; ++nf) {
                const int p = nf * 16 + lm;
                bf16x8 bf = *(const bf16x8*)(
                    (const char*)Bs + p * 256 + (((kt * 4 + q4) ^ (lm & 7)) * 16));
                acc[nf] = MFMA(af[kt], bf, acc[nf], 0, 0, 0);
            }
        }
        const int og0 = o0 + q4 * 4;
#pragma unroll
        for (int nf = 0; nf < 4; ++nf) {
            const int p_g = p0 + nf * 16 + lm;
#pragma unroll
            for (int r = 0; r < 4; ++r)
                out[((size_t)(b * CDIM + og0 + r)) * NTOK + p_g] =
                    acc[nf][r] + bias[og0 + r];
        }
    }
}

// ---------------------------------------------------------------------------
extern "C" void kernel_launch(void* const* d_in, const int* in_sizes, int n_in,
                              void* d_out, int out_size, void* d_ws, size_t ws_size,
                              hipStream_t stream)
{
    const float* x     = (const float*)d_in[0];
    const float* w_qkv = (const float*)d_in[1];
    const float* w_out = (const float*)d_in[2];
    const float* b_out = (const float*)d_in[3];
    float* out = (float*)d_out;

    __bf16* Q  = (__bf16*)d_ws;                           // 4 MB each
    __bf16* K  = Q  + (size_t)16 * NTOK * DHEAD;
    __bf16* Vt = K  + (size_t)16 * NTOK * DHEAD;
    __bf16* Opart = Vt + (size_t)16 * NTOK * DHEAD;       // 4 x 4 MB (bf16)
    float*  Lsum  = (float*)(Opart + (size_t)4 * NBATCH * NTOK * HID); // 4x256 KB

    qkv_fused<<<dim3(64, NBATCH), 256, 0, stream>>>(x, w_qkv, Q, K, Vt);
    attn     <<<1024, 256, 0, stream>>>(Q, K, Vt, Opart, Lsum);
    out_fused<<<dim3(64, NBATCH), 256, 0, stream>>>(w_out, Opart, Lsum, b_out, out);
}